// Round 11
// baseline (107.807 us; speedup 1.0000x reference)
//
#include <hip/hip_runtime.h>
#include <math.h>
#include <stdint.h>

#define NB 4
#define CC 256
#define HWD 4096
#define NPIX (NB * HWD)

typedef __attribute__((ext_vector_type(8))) short bf16x8;
typedef __attribute__((ext_vector_type(4))) float f32x4;

#define VMW8()  asm volatile("s_waitcnt vmcnt(8)" ::: "memory")
#define VMW0()  asm volatile("s_waitcnt vmcnt(0)" ::: "memory")
#define LGKM0() asm volatile("s_waitcnt lgkmcnt(0)" ::: "memory")
#define SCHED0() __builtin_amdgcn_sched_barrier(0)
#define SBAR()  __builtin_amdgcn_s_barrier()

__device__ __forceinline__ void gload16(const void* g, void* l) {
    using GP = const __attribute__((address_space(1))) uint32_t*;
    using LP = __attribute__((address_space(3))) uint32_t*;
    __builtin_amdgcn_global_load_lds((GP)g, (LP)l, 16, 0, 0);
}

// sum over each 16-lane DPP row; result valid in lane (rl==15) of each row
__device__ __forceinline__ float dpp_rowsum16(float v) {
    v += __int_as_float(__builtin_amdgcn_update_dpp(0, __float_as_int(v), 0x111, 0xf, 0xf, true));
    v += __int_as_float(__builtin_amdgcn_update_dpp(0, __float_as_int(v), 0x112, 0xf, 0xf, true));
    v += __int_as_float(__builtin_amdgcn_update_dpp(0, __float_as_int(v), 0x114, 0xf, 0xf, true));
    v += __int_as_float(__builtin_amdgcn_update_dpp(0, __float_as_int(v), 0x118, 0xf, 0xf, true));
    return v;
}

// ---------------- kernel 1: per-pixel L2 norm + scale + bf16 + transpose ----------------
__global__ __launch_bounds__(512) void normcvt(
    const float* __restrict__ rgb, const float* __restrict__ ir,
    ushort* __restrict__ Abf, ushort* __restrict__ Bbf)
{
    __shared__ float ssbuf[8][64];
    __shared__ float rnl[64];
    const float* src = blockIdx.y ? ir : rgb;
    ushort* dst = blockIdx.y ? Bbf : Abf;
    const int t = threadIdx.x;
    const int p = t & 63, sg = t >> 6;
    const int P = blockIdx.x * 64 + p;
    const int n = P >> 12, pl = P & (HWD - 1);
    const float* base = src + ((size_t)n * CC) * HWD + pl;
    const int c0 = sg * 32;

    float x[32];
    float ss = 0.f;
#pragma unroll
    for (int i = 0; i < 32; ++i) {
        x[i] = base[(size_t)(c0 + i) * HWD];
        ss = fmaf(x[i], x[i], ss);
    }
    ssbuf[sg][p] = ss;
    __syncthreads();
    if (t < 64) {
        float s2 = 0.f;
#pragma unroll
        for (int g = 0; g < 8; ++g) s2 += ssbuf[g][t];
        rnl[t] = 1.0f / fmaxf(sqrtf(s2), 1e-12f);
    }
    __syncthreads();
    const float rn = rnl[p];

    uint pk[16];
#pragma unroll
    for (int i = 0; i < 16; ++i) {
        float x0 = x[2 * i] * rn;
        float x1 = x[2 * i + 1] * rn;
        uint u0 = __float_as_uint(x0); u0 += 0x7fffu + ((u0 >> 16) & 1u);  // RNE bf16
        uint u1 = __float_as_uint(x1); u1 += 0x7fffu + ((u1 >> 16) & 1u);
        pk[i] = (u0 >> 16) | (u1 & 0xffff0000u);
    }
    uint4* o = (uint4*)(dst + (size_t)P * CC + c0);
#pragma unroll
    for (int k = 0; k < 4; ++k)
        o[k] = make_uint4(pk[4 * k], pk[4 * k + 1], pk[4 * k + 2], pk[4 * k + 3]);
}

// ---------------- kernel 2: 256x256-tile bf16 MFMA GEMM ----------------
// 8 waves (2x4 of 128x64), BK=64, 128KB LDS dbuf (1 block/CU, 2 waves/SIMD),
// counted vmcnt(8), single-half fragment liveness (a[8],b[4] reused across halves;
// half1 LDS addr = half0 addr XOR 64B), partial-sum epilogue (no atomics).
__global__ __launch_bounds__(512, 2) void gemm_mfma(
    const ushort* __restrict__ Abf, const ushort* __restrict__ Bbf,
    const int* __restrict__ rmask, const int* __restrict__ imask,
    float2* __restrict__ prow, float2* __restrict__ pcol)
{
    __shared__ __align__(16) ushort As[2][256][64];   // 64 KB
    __shared__ __align__(16) ushort Bs[2][256][64];   // 64 KB

    // XCD-aware bijective swizzle: 1024 blocks, 128 consecutive per XCD
    const int id = blockIdx.x;
    const int swz = (id & 7) * 128 + (id >> 3);
    const int n  = swz >> 8;
    const int pq = swz & 255;
    const int pt = pq >> 4, qt = pq & 15;
    const int p0 = pt * 256, q0 = qt * 256;

    const int t = threadIdx.x;
    const int lane = t & 63;
    const int wv = t >> 6;                    // 0..7
    const int wr = wv >> 2, wc = wv & 3;      // 2 x 4 wave grid; wave tile 128x64
    const int kg = lane >> 4, rl = lane & 15;

    const ushort* Ab = Abf + ((size_t)n * HWD + p0) * CC;
    const ushort* Bb = Bbf + ((size_t)n * HWD + q0) * CC;

    // ---- hoisted stage addresses: 4 its x (A,B); 2048 16B-slots per matrix per tile ----
    // slot -> row r = slot>>3, pos = slot&7; global chunk pre-swizzled g = pos ^ (r&7)
    const ushort* gA[4]; const ushort* gB[4];
    char* lA[4]; char* lB[4];
#pragma unroll
    for (int it = 0; it < 4; ++it) {
        int slot = it * 512 + t;              // 0..2047
        int r = slot >> 3, pos = slot & 7;
        int g = pos ^ (r & 7);
        gA[it] = Ab + (size_t)r * CC + g * 8;
        gB[it] = Bb + (size_t)r * CC + g * 8;
        lA[it] = ((char*)As) + it * 8192 + wv * 1024;
        lB[it] = ((char*)Bs) + it * 8192 + wv * 1024;
    }
    // one buffer = 256*64*2 = 32768 bytes -> BUFB in {0, 32768}
#define STAGE(BUFB, C0)                                                        \
    {                                                                          \
        _Pragma("unroll")                                                      \
        for (int it = 0; it < 4; ++it) {                                       \
            gload16(gA[it] + (C0), lA[it] + (BUFB));                           \
            gload16(gB[it] + (C0), lB[it] + (BUFB));                           \
        }                                                                      \
    }

    // ---- hoisted fragment LDS pointers (buf0, half ks=0); buf1 = +16384 ushorts ----
    const ushort* ap[8]; const ushort* bp[4];
#pragma unroll
    for (int mi = 0; mi < 8; ++mi) {
        int r = wr * 128 + mi * 16 + rl;
        ap[mi] = &As[0][r][((kg ^ (r & 7)) * 8)];
    }
#pragma unroll
    for (int ni = 0; ni < 4; ++ni) {
        int r = wc * 64 + ni * 16 + rl;
        bp[ni] = &Bs[0][r][((kg ^ (r & 7)) * 8)];
    }

    f32x4 acc[8][4];
#pragma unroll
    for (int mi = 0; mi < 8; ++mi)
#pragma unroll
        for (int ni = 0; ni < 4; ++ni) acc[mi][ni] = (f32x4){0.f, 0.f, 0.f, 0.f};

    STAGE(0, 0);          // 8 loads/thread in flight
    STAGE(32768, 64);     // 16 in flight
    SCHED0();

#define KITER(BUF, VMWAIT, RESTAGE)                                            \
    {                                                                          \
        VMWAIT;                                                                \
        SCHED0();                                                              \
        SBAR();                                                                \
        SCHED0();                                                              \
        bf16x8 a[8], b[4];                                                     \
        _Pragma("unroll")                                                      \
        for (int mi = 0; mi < 8; ++mi)                                         \
            a[mi] = *(const bf16x8*)(ap[mi] + (BUF) * 16384);                  \
        _Pragma("unroll")                                                      \
        for (int ni = 0; ni < 4; ++ni)                                         \
            b[ni] = *(const bf16x8*)(bp[ni] + (BUF) * 16384);                  \
        LGKM0();                                                               \
        SCHED0();                                                              \
        __builtin_amdgcn_s_setprio(1);                                         \
        _Pragma("unroll")                                                      \
        for (int mi = 0; mi < 8; ++mi)                                         \
            _Pragma("unroll")                                                  \
            for (int ni = 0; ni < 4; ++ni)                                     \
                acc[mi][ni] = __builtin_amdgcn_mfma_f32_16x16x32_bf16(         \
                    a[mi], b[ni], acc[mi][ni], 0, 0, 0);                       \
        __builtin_amdgcn_s_setprio(0);                                         \
        SCHED0();                                                              \
        _Pragma("unroll")                                                      \
        for (int mi = 0; mi < 8; ++mi)                                         \
            a[mi] = *(const bf16x8*)((uintptr_t)(ap[mi] + (BUF) * 16384) ^ 64);\
        _Pragma("unroll")                                                      \
        for (int ni = 0; ni < 4; ++ni)                                         \
            b[ni] = *(const bf16x8*)((uintptr_t)(bp[ni] + (BUF) * 16384) ^ 64);\
        LGKM0();                                                               \
        SCHED0();                                                              \
        SBAR();                                                                \
        SCHED0();                                                              \
        RESTAGE;                                                               \
        __builtin_amdgcn_s_setprio(1);                                         \
        _Pragma("unroll")                                                      \
        for (int mi = 0; mi < 8; ++mi)                                         \
            _Pragma("unroll")                                                  \
            for (int ni = 0; ni < 4; ++ni)                                     \
                acc[mi][ni] = __builtin_amdgcn_mfma_f32_16x16x32_bf16(         \
                    a[mi], b[ni], acc[mi][ni], 0, 0, 0);                       \
        __builtin_amdgcn_s_setprio(0);                                         \
        SCHED0();                                                              \
    }

    KITER(0, VMW8(), STAGE(0, 128));
    KITER(1, VMW8(), STAGE(32768, 192));
    KITER(0, VMW8(), );
    KITER(1, VMW0(), );
#undef KITER
#undef STAGE

    // ---- epilogue: clamp, exp, mask, block-local reduce, partial store (no atomics) ----
    const int* rmp = rmask + (size_t)n * HWD + p0 + wr * 128;
    const int* imp = imask + (size_t)n * HWD + q0 + wc * 64;
    int clab[4];
#pragma unroll
    for (int ni = 0; ni < 4; ++ni) clab[ni] = imp[ni * 16 + rl];

    // LDS scratch aliasing As (all LDS reads completed before last KITER's 2nd barrier)
    float* rb = (float*)As;      // [wc:4][nd:2][256 rows] = 2048 floats
    float* cb = rb + 2048;       // [wr:2][nd:2][256 cols] = 1024 floats

    const float SC = 28.853900817779268f;   // 20 * log2(e)
    float cn[4] = {0.f, 0.f, 0.f, 0.f}, cd[4] = {0.f, 0.f, 0.f, 0.f};

#pragma unroll
    for (int mi = 0; mi < 8; ++mi) {
        int4 r4 = *(const int4*)(rmp + mi * 16 + kg * 4);
        int rlab[4] = {r4.x, r4.y, r4.z, r4.w};
        float rn4[4] = {0.f, 0.f, 0.f, 0.f}, rd4[4] = {0.f, 0.f, 0.f, 0.f};
#pragma unroll
        for (int ni = 0; ni < 4; ++ni) {
#pragma unroll
            for (int j = 0; j < 4; ++j) {
                float s = fminf(fmaxf(acc[mi][ni][j], -1.f), 1.f);
                float e = exp2f(s * SC);
                rd4[j] += e;
                cd[ni] += e;
                bool m = (rlab[j] == clab[ni]);
                rn4[j] += m ? e : 0.f;
                cn[ni] += m ? e : 0.f;
            }
        }
#pragma unroll
        for (int j = 0; j < 4; ++j) {
            rn4[j] = dpp_rowsum16(rn4[j]);
            rd4[j] = dpp_rowsum16(rd4[j]);
        }
        if (rl == 15) {
            int row = wr * 128 + mi * 16 + kg * 4;
#pragma unroll
            for (int j = 0; j < 4; ++j) {
                rb[(wc * 2 + 0) * 256 + row + j] = rn4[j];
                rb[(wc * 2 + 1) * 256 + row + j] = rd4[j];
            }
        }
    }
#pragma unroll
    for (int ni = 0; ni < 4; ++ni) {
        cn[ni] += __shfl_xor(cn[ni], 16); cn[ni] += __shfl_xor(cn[ni], 32);
        cd[ni] += __shfl_xor(cd[ni], 16); cd[ni] += __shfl_xor(cd[ni], 32);
    }
    if (kg == 0) {
#pragma unroll
        for (int ni = 0; ni < 4; ++ni) {
            int col = wc * 64 + ni * 16 + rl;
            cb[(wr * 2 + 0) * 256 + col] = cn[ni];
            cb[(wr * 2 + 1) * 256 + col] = cd[ni];
        }
    }
    __syncthreads();
    if (t < 256) {
        float2 r2 = make_float2(rb[t] + rb[512 + t] + rb[1024 + t] + rb[1536 + t],
                                rb[256 + t] + rb[768 + t] + rb[1280 + t] + rb[1792 + t]);
        prow[(size_t)qt * NPIX + (size_t)n * HWD + p0 + t] = r2;
    } else {
        int c = t - 256;
        float2 c2 = make_float2(cb[c] + cb[512 + c], cb[256 + c] + cb[768 + c]);
        pcol[(size_t)pt * NPIX + (size_t)n * HWD + q0 + c] = c2;
    }
}

// ---------------- kernel 3: reduce partials + loss entries + global reduce ----------------
__global__ __launch_bounds__(256) void loss_reduce(
    const float2* __restrict__ prow, const float2* __restrict__ pcol,
    const int* __restrict__ rmask, const int* __restrict__ imask,
    float* __restrict__ accum)
{
    __shared__ float sbuf[2][4];
    int idx = blockIdx.x * 256 + threadIdx.x;   // 0 .. 2*NPIX-1
    float num = 0.f, den = 0.f; int fg;
    if (idx < NPIX) {
        fg = rmask[idx] > 0;
#pragma unroll
        for (int q = 0; q < 16; ++q) {
            float2 v = prow[(size_t)q * NPIX + idx];
            num += v.x; den += v.y;
        }
    } else {
        int k = idx - NPIX;
        fg = imask[k] > 0;
#pragma unroll
        for (int p = 0; p < 16; ++p) {
            float2 v = pcol[(size_t)p * NPIX + k];
            num += v.x; den += v.y;
        }
    }
    float v = 0.f, cnt = 0.f;
    if (fg && num > 0.f) {
        float r = num / (den + 1e-6f);
        v = -__logf(r);
        cnt = 1.f;
    }
#pragma unroll
    for (int m = 1; m <= 32; m <<= 1) {
        v += __shfl_xor(v, m);
        cnt += __shfl_xor(cnt, m);
    }
    int lane = threadIdx.x & 63, wave = threadIdx.x >> 6;
    if (lane == 0) { sbuf[0][wave] = v; sbuf[1][wave] = cnt; }
    __syncthreads();
    if (threadIdx.x == 0) {
        atomicAdd(&accum[0], sbuf[0][0] + sbuf[0][1] + sbuf[0][2] + sbuf[0][3]);
        atomicAdd(&accum[1], sbuf[1][0] + sbuf[1][1] + sbuf[1][2] + sbuf[1][3]);
    }
}

__global__ void finalize(const float* __restrict__ accum, float* __restrict__ out) {
    out[0] = accum[0] / fmaxf(accum[1], 1.0f);
}

// ---------------- launch ----------------
extern "C" void kernel_launch(void* const* d_in, const int* in_sizes, int n_in,
                              void* d_out, int out_size, void* d_ws, size_t ws_size,
                              hipStream_t stream) {
    const float* rgb = (const float*)d_in[0];
    const float* ir  = (const float*)d_in[1];
    const int* rm = (const int*)d_in[2];
    const int* im = (const int*)d_in[3];
    float* out = (float*)d_out;

    const size_t NE = (size_t)NPIX * CC;         // 4M bf16 per array
    ushort* Abf = (ushort*)d_ws;
    ushort* Bbf = Abf + NE;
    float2* prow = (float2*)(Bbf + NE);          // 16 * NPIX float2 = 2 MB
    float2* pcol = prow + (size_t)16 * NPIX;     // 2 MB
    float* accum = (float*)(pcol + (size_t)16 * NPIX);  // 2 floats

    hipMemsetAsync(accum, 0, 2 * sizeof(float), stream);

    normcvt<<<dim3(NPIX / 64, 2), 512, 0, stream>>>(rgb, ir, Abf, Bbf);
    gemm_mfma<<<dim3(1024), 512, 0, stream>>>(
        Abf, Bbf, rm, im, prow, pcol);
    loss_reduce<<<(2 * NPIX) / 256, 256, 0, stream>>>(prow, pcol, rm, im, accum);
    finalize<<<1, 1, 0, stream>>>(accum, out);
}

// Round 12
// 87.982 us; speedup vs baseline: 1.2253x; 1.2253x over previous
//
#include <hip/hip_runtime.h>
#include <math.h>
#include <stdint.h>

#define NB 4
#define CC 256
#define HWD 4096
#define NPIX (NB * HWD)

typedef __attribute__((ext_vector_type(8))) short bf16x8;
typedef __attribute__((ext_vector_type(4))) float f32x4;

#define VMW8()  asm volatile("s_waitcnt vmcnt(8)" ::: "memory")
#define VMW4()  asm volatile("s_waitcnt vmcnt(4)" ::: "memory")
#define VMW0()  asm volatile("s_waitcnt vmcnt(0)" ::: "memory")
#define LGKM0() asm volatile("s_waitcnt lgkmcnt(0)" ::: "memory")
#define SCHED0() __builtin_amdgcn_sched_barrier(0)
#define SBAR()  __builtin_amdgcn_s_barrier()

__device__ __forceinline__ void gload16(const void* g, void* l) {
    using GP = const __attribute__((address_space(1))) uint32_t*;
    using LP = __attribute__((address_space(3))) uint32_t*;
    __builtin_amdgcn_global_load_lds((GP)g, (LP)l, 16, 0, 0);
}

// sum over each 16-lane DPP row; result valid in lane (rl==15) of each row
__device__ __forceinline__ float dpp_rowsum16(float v) {
    v += __int_as_float(__builtin_amdgcn_update_dpp(0, __float_as_int(v), 0x111, 0xf, 0xf, true));
    v += __int_as_float(__builtin_amdgcn_update_dpp(0, __float_as_int(v), 0x112, 0xf, 0xf, true));
    v += __int_as_float(__builtin_amdgcn_update_dpp(0, __float_as_int(v), 0x114, 0xf, 0xf, true));
    v += __int_as_float(__builtin_amdgcn_update_dpp(0, __float_as_int(v), 0x118, 0xf, 0xf, true));
    return v;
}

// ---------------- kernel 1: per-pixel L2 norm + scale + bf16 + transpose ----------------
__global__ __launch_bounds__(512) void normcvt(
    const float* __restrict__ rgb, const float* __restrict__ ir,
    ushort* __restrict__ Abf, ushort* __restrict__ Bbf)
{
    __shared__ float ssbuf[8][64];
    __shared__ float rnl[64];
    const float* src = blockIdx.y ? ir : rgb;
    ushort* dst = blockIdx.y ? Bbf : Abf;
    const int t = threadIdx.x;
    const int p = t & 63, sg = t >> 6;
    const int P = blockIdx.x * 64 + p;
    const int n = P >> 12, pl = P & (HWD - 1);
    const float* base = src + ((size_t)n * CC) * HWD + pl;
    const int c0 = sg * 32;

    float x[32];
    float ss = 0.f;
#pragma unroll
    for (int i = 0; i < 32; ++i) {
        x[i] = base[(size_t)(c0 + i) * HWD];
        ss = fmaf(x[i], x[i], ss);
    }
    ssbuf[sg][p] = ss;
    __syncthreads();
    if (t < 64) {
        float s2 = 0.f;
#pragma unroll
        for (int g = 0; g < 8; ++g) s2 += ssbuf[g][t];
        rnl[t] = 1.0f / fmaxf(sqrtf(s2), 1e-12f);
    }
    __syncthreads();
    const float rn = rnl[p];

    uint pk[16];
#pragma unroll
    for (int i = 0; i < 16; ++i) {
        float x0 = x[2 * i] * rn;
        float x1 = x[2 * i + 1] * rn;
        uint u0 = __float_as_uint(x0); u0 += 0x7fffu + ((u0 >> 16) & 1u);  // RNE bf16
        uint u1 = __float_as_uint(x1); u1 += 0x7fffu + ((u1 >> 16) & 1u);
        pk[i] = (u0 >> 16) | (u1 & 0xffff0000u);
    }
    uint4* o = (uint4*)(dst + (size_t)P * CC + c0);
#pragma unroll
    for (int k = 0; k < 4; ++k)
        o[k] = make_uint4(pk[4 * k], pk[4 * k + 1], pk[4 * k + 2], pk[4 * k + 3]);
}

// ---------------- kernel 2: 128x128-tile bf16 MFMA GEMM, triple-buffer, 1 barrier/K-step ----
// 4 waves (2x2 of 64x64), BK=32, 3x16KB LDS (3 blocks/CU), counted vmcnt (never 0
// mid-loop), 3-deep prefetch. Restage target = buffer freed LAST iter, so no
// second barrier is needed. Partial-sum epilogue (no atomics).
__global__ __launch_bounds__(256, 2) void gemm_mfma(
    const ushort* __restrict__ Abf, const ushort* __restrict__ Bbf,
    const int* __restrict__ rmask, const int* __restrict__ imask,
    float2* __restrict__ prow, float2* __restrict__ pcol)
{
    __shared__ __align__(16) ushort As[3][128][32];   // 24 KB
    __shared__ __align__(16) ushort Bs[3][128][32];   // 24 KB

    const int n  = blockIdx.z;
    // XCD-aware bijective swizzle within the 32x32 slice (1024 % 8 == 0)
    const int lin = blockIdx.y * 32 + blockIdx.x;
    const int swz = (lin & 7) * 128 + (lin >> 3);
    const int qt = swz & 31, pt = swz >> 5;
    const int q0 = qt * 128, p0 = pt * 128;

    const int t  = threadIdx.x;
    const int lane = t & 63;
    const int wv = t >> 6, wr = wv >> 1, wc = wv & 1;
    const int kg = lane >> 4, rl = lane & 15;

    const ushort* Ab = Abf + ((size_t)n * HWD + p0) * CC;
    const ushort* Bb = Bbf + ((size_t)n * HWD + q0) * CC;

    // ---- hoisted stage addresses: 2 its x (A,B); 512 16B-slots per matrix ----
    // slot -> row r = slot>>2, pos = slot&3; global chunk pre-swizzled g = pos ^ ((r>>1)&3)
    const ushort* gA[2]; const ushort* gB[2];
    char* lA[2]; char* lB[2];
#pragma unroll
    for (int it = 0; it < 2; ++it) {
        int slot = it * 256 + t;
        int r = slot >> 2, pos = slot & 3;
        int g = pos ^ ((r >> 1) & 3);
        gA[it] = Ab + (size_t)r * CC + g * 8;
        gB[it] = Bb + (size_t)r * CC + g * 8;
        lA[it] = ((char*)As) + it * 4096 + (t & 192) * 16;
        lB[it] = ((char*)Bs) + it * 4096 + (t & 192) * 16;
    }
    // one buffer = 128*32*2 = 8192 bytes -> BUFB in {0, 8192, 16384}
#define STAGE(BUFB, C0)                                                        \
    {                                                                          \
        _Pragma("unroll")                                                      \
        for (int it = 0; it < 2; ++it) {                                       \
            gload16(gA[it] + (C0), lA[it] + (BUFB));                           \
            gload16(gB[it] + (C0), lB[it] + (BUFB));                           \
        }                                                                      \
    }

    // ---- hoisted fragment LDS pointers (buf0); buf k = +k*4096 ushorts ----
    const ushort* ap[4]; const ushort* bp[4];
#pragma unroll
    for (int mi = 0; mi < 4; ++mi) {
        int r = wr * 64 + mi * 16 + rl;
        ap[mi] = &As[0][r][((kg ^ ((r >> 1) & 3)) * 8)];
    }
#pragma unroll
    for (int ni = 0; ni < 4; ++ni) {
        int r = wc * 64 + ni * 16 + rl;
        bp[ni] = &Bs[0][r][((kg ^ ((r >> 1) & 3)) * 8)];
    }

    f32x4 acc[4][4];
#pragma unroll
    for (int mi = 0; mi < 4; ++mi)
#pragma unroll
        for (int ni = 0; ni < 4; ++ni) acc[mi][ni] = (f32x4){0.f, 0.f, 0.f, 0.f};

    STAGE(0, 0);         // K-step 0 -> buf0 (4 loads in flight)
    STAGE(8192, 32);     // K-step 1 -> buf1 (8)
    STAGE(16384, 64);    // K-step 2 -> buf2 (12)
    SCHED0();

    // One barrier per K-step. RESTAGE writes the buffer freed last iter
    // (all waves' lgkmcnt(0) for it preceded the barrier they already crossed).
#define KITER(BUF, VMWAIT, RESTAGE)                                            \
    {                                                                          \
        VMWAIT;                                                                \
        SCHED0();                                                              \
        SBAR();                                                                \
        SCHED0();                                                              \
        RESTAGE;                                                               \
        bf16x8 a[4], b[4];                                                     \
        _Pragma("unroll")                                                      \
        for (int mi = 0; mi < 4; ++mi)                                         \
            a[mi] = *(const bf16x8*)(ap[mi] + (BUF) * 4096);                   \
        _Pragma("unroll")                                                      \
        for (int ni = 0; ni < 4; ++ni)                                         \
            b[ni] = *(const bf16x8*)(bp[ni] + (BUF) * 4096);                   \
        LGKM0();                                                               \
        SCHED0();                                                              \
        __builtin_amdgcn_s_setprio(1);                                         \
        _Pragma("unroll")                                                      \
        for (int mi = 0; mi < 4; ++mi)                                         \
            _Pragma("unroll")                                                  \
            for (int ni = 0; ni < 4; ++ni)                                     \
                acc[mi][ni] = __builtin_amdgcn_mfma_f32_16x16x32_bf16(         \
                    a[mi], b[ni], acc[mi][ni], 0, 0, 0);                       \
        __builtin_amdgcn_s_setprio(0);                                         \
        SCHED0();                                                              \
    }

    KITER(0, VMW8(), );                       // step 0 (buf0); stages 1,2 in flight
    KITER(1, VMW4(), STAGE(0, 96));           // step 1; stage step3 -> buf0
    KITER(2, VMW4(), STAGE(8192, 128));       // step 2; stage step4 -> buf1
    KITER(0, VMW4(), STAGE(16384, 160));      // step 3; stage step5 -> buf2
    KITER(1, VMW4(), STAGE(0, 192));          // step 4; stage step6 -> buf0
    KITER(2, VMW4(), STAGE(8192, 224));       // step 5; stage step7 -> buf1
    KITER(0, VMW4(), );                       // step 6
    KITER(1, VMW0(), );                       // step 7
#undef KITER
#undef STAGE

    // ---- epilogue: clamp, exp, mask, block-local reduce, partial store (no atomics) ----
    const int* rmp = rmask + (size_t)n * HWD + p0 + wr * 64;
    const int* imp = imask + (size_t)n * HWD + q0 + wc * 64;
    int clab[4];
#pragma unroll
    for (int ni = 0; ni < 4; ++ni) clab[ni] = imp[ni * 16 + rl];

    // LDS scratch aliasing As buf0 (4 KB; buf0 last read at step 6 — all waves
    // passed lgkmcnt(0) for it before the step-7 barrier). Step 7 reads buf1 only.
    float* rb = (float*)As;      // [wc][nd][128 rows] = 512 floats
    float* cb = rb + 512;        // [wr][nd][128 cols] = 512 floats

    const float SC = 28.853900817779268f;   // 20 * log2(e)
    float cn[4] = {0.f, 0.f, 0.f, 0.f}, cd[4] = {0.f, 0.f, 0.f, 0.f};

#pragma unroll
    for (int mi = 0; mi < 4; ++mi) {
        int4 r4 = *(const int4*)(rmp + mi * 16 + kg * 4);
        int rlab[4] = {r4.x, r4.y, r4.z, r4.w};
        float rn4[4] = {0.f, 0.f, 0.f, 0.f}, rd4[4] = {0.f, 0.f, 0.f, 0.f};
#pragma unroll
        for (int ni = 0; ni < 4; ++ni) {
#pragma unroll
            for (int j = 0; j < 4; ++j) {
                float s = fminf(fmaxf(acc[mi][ni][j], -1.f), 1.f);
                float e = exp2f(s * SC);
                rd4[j] += e;
                cd[ni] += e;
                bool m = (rlab[j] == clab[ni]);
                rn4[j] += m ? e : 0.f;
                cn[ni] += m ? e : 0.f;
            }
        }
#pragma unroll
        for (int j = 0; j < 4; ++j) {
            rn4[j] = dpp_rowsum16(rn4[j]);
            rd4[j] = dpp_rowsum16(rd4[j]);
        }
        if (rl == 15) {
            int row = wr * 64 + mi * 16 + kg * 4;
#pragma unroll
            for (int j = 0; j < 4; ++j) {
                rb[(wc * 2 + 0) * 128 + row + j] = rn4[j];
                rb[(wc * 2 + 1) * 128 + row + j] = rd4[j];
            }
        }
    }
#pragma unroll
    for (int ni = 0; ni < 4; ++ni) {
        cn[ni] += __shfl_xor(cn[ni], 16); cn[ni] += __shfl_xor(cn[ni], 32);
        cd[ni] += __shfl_xor(cd[ni], 16); cd[ni] += __shfl_xor(cd[ni], 32);
    }
    if (kg == 0) {
#pragma unroll
        for (int ni = 0; ni < 4; ++ni) {
            int col = wc * 64 + ni * 16 + rl;
            cb[(wr * 2 + 0) * 128 + col] = cn[ni];
            cb[(wr * 2 + 1) * 128 + col] = cd[ni];
        }
    }
    __syncthreads();
    if (t < 128) {
        float2 r2 = make_float2(rb[t] + rb[256 + t], rb[128 + t] + rb[384 + t]);
        prow[(size_t)qt * NPIX + (size_t)n * HWD + p0 + t] = r2;
        float2 c2 = make_float2(cb[t] + cb[256 + t], cb[128 + t] + cb[384 + t]);
        pcol[(size_t)pt * NPIX + (size_t)n * HWD + q0 + t] = c2;
    }
}

// ---------------- kernel 3: reduce partials + loss entries + global reduce ----------------
__global__ __launch_bounds__(256) void loss_reduce(
    const float2* __restrict__ prow, const float2* __restrict__ pcol,
    const int* __restrict__ rmask, const int* __restrict__ imask,
    float* __restrict__ accum)
{
    __shared__ float sbuf[2][4];
    int idx = blockIdx.x * 256 + threadIdx.x;   // 0 .. 2*NPIX-1
    float num = 0.f, den = 0.f; int fg;
    if (idx < NPIX) {
        fg = rmask[idx] > 0;
#pragma unroll 8
        for (int q = 0; q < 32; ++q) {
            float2 v = prow[(size_t)q * NPIX + idx];
            num += v.x; den += v.y;
        }
    } else {
        int k = idx - NPIX;
        fg = imask[k] > 0;
#pragma unroll 8
        for (int p = 0; p < 32; ++p) {
            float2 v = pcol[(size_t)p * NPIX + k];
            num += v.x; den += v.y;
        }
    }
    float v = 0.f, cnt = 0.f;
    if (fg && num > 0.f) {
        float r = num / (den + 1e-6f);
        v = -__logf(r);
        cnt = 1.f;
    }
#pragma unroll
    for (int m = 1; m <= 32; m <<= 1) {
        v += __shfl_xor(v, m);
        cnt += __shfl_xor(cnt, m);
    }
    int lane = threadIdx.x & 63, wave = threadIdx.x >> 6;
    if (lane == 0) { sbuf[0][wave] = v; sbuf[1][wave] = cnt; }
    __syncthreads();
    if (threadIdx.x == 0) {
        atomicAdd(&accum[0], sbuf[0][0] + sbuf[0][1] + sbuf[0][2] + sbuf[0][3]);
        atomicAdd(&accum[1], sbuf[1][0] + sbuf[1][1] + sbuf[1][2] + sbuf[1][3]);
    }
}

__global__ void finalize(const float* __restrict__ accum, float* __restrict__ out) {
    out[0] = accum[0] / fmaxf(accum[1], 1.0f);
}

// ---------------- launch ----------------
extern "C" void kernel_launch(void* const* d_in, const int* in_sizes, int n_in,
                              void* d_out, int out_size, void* d_ws, size_t ws_size,
                              hipStream_t stream) {
    const float* rgb = (const float*)d_in[0];
    const float* ir  = (const float*)d_in[1];
    const int* rm = (const int*)d_in[2];
    const int* im = (const int*)d_in[3];
    float* out = (float*)d_out;

    const size_t NE = (size_t)NPIX * CC;         // 4M bf16 per array
    ushort* Abf = (ushort*)d_ws;
    ushort* Bbf = Abf + NE;
    float2* prow = (float2*)(Bbf + NE);          // 32 * NPIX float2 = 4 MB
    float2* pcol = prow + (size_t)32 * NPIX;     // 4 MB
    float* accum = (float*)(pcol + (size_t)32 * NPIX);  // 2 floats

    hipMemsetAsync(accum, 0, 2 * sizeof(float), stream);

    normcvt<<<dim3(NPIX / 64, 2), 512, 0, stream>>>(rgb, ir, Abf, Bbf);
    gemm_mfma<<<dim3(HWD / 128, HWD / 128, NB), 256, 0, stream>>>(
        Abf, Bbf, rm, im, prow, pcol);
    loss_reduce<<<(2 * NPIX) / 256, 256, 0, stream>>>(prow, pcol, rm, im, accum);
    finalize<<<1, 1, 0, stream>>>(accum, out);
}

// Round 13
// 78.413 us; speedup vs baseline: 1.3748x; 1.1220x over previous
//
#include <hip/hip_runtime.h>
#include <math.h>
#include <stdint.h>

#define NB 4
#define CC 256
#define HWD 4096
#define NPIX (NB * HWD)

typedef __attribute__((ext_vector_type(4))) float f32x4;
typedef unsigned long long u64;

#define VMW8()  asm volatile("s_waitcnt vmcnt(8)" ::: "memory")
#define VMW4()  asm volatile("s_waitcnt vmcnt(4)" ::: "memory")
#define VMW0()  asm volatile("s_waitcnt vmcnt(0)" ::: "memory")
#define LGKM0() asm volatile("s_waitcnt lgkmcnt(0)" ::: "memory")
#define SCHED0() __builtin_amdgcn_sched_barrier(0)
#define SBAR()  __builtin_amdgcn_s_barrier()

__device__ __forceinline__ void gload16(const void* g, void* l) {
    using GP = const __attribute__((address_space(1))) uint32_t*;
    using LP = __attribute__((address_space(3))) uint32_t*;
    __builtin_amdgcn_global_load_lds((GP)g, (LP)l, 16, 0, 0);
}

// sum over each 16-lane DPP row; result valid in lane (rl==15) of each row
__device__ __forceinline__ float dpp_rowsum16(float v) {
    v += __int_as_float(__builtin_amdgcn_update_dpp(0, __float_as_int(v), 0x111, 0xf, 0xf, true));
    v += __int_as_float(__builtin_amdgcn_update_dpp(0, __float_as_int(v), 0x112, 0xf, 0xf, true));
    v += __int_as_float(__builtin_amdgcn_update_dpp(0, __float_as_int(v), 0x114, 0xf, 0xf, true));
    v += __int_as_float(__builtin_amdgcn_update_dpp(0, __float_as_int(v), 0x118, 0xf, 0xf, true));
    return v;
}

// ---------------- kernel 1: per-pixel L2 norm + scale + fp8(e4m3) + transpose ----------------
__global__ __launch_bounds__(512) void normcvt(
    const float* __restrict__ rgb, const float* __restrict__ ir,
    unsigned char* __restrict__ Abf, unsigned char* __restrict__ Bbf)
{
    __shared__ float ssbuf[8][64];
    __shared__ float rnl[64];
    const float* src = blockIdx.y ? ir : rgb;
    unsigned char* dst = blockIdx.y ? Bbf : Abf;
    const int t = threadIdx.x;
    const int p = t & 63, sg = t >> 6;
    const int P = blockIdx.x * 64 + p;
    const int n = P >> 12, pl = P & (HWD - 1);
    const float* base = src + ((size_t)n * CC) * HWD + pl;
    const int c0 = sg * 32;

    float x[32];
    float ss = 0.f;
#pragma unroll
    for (int i = 0; i < 32; ++i) {
        x[i] = base[(size_t)(c0 + i) * HWD];
        ss = fmaf(x[i], x[i], ss);
    }
    ssbuf[sg][p] = ss;
    __syncthreads();
    if (t < 64) {
        float s2 = 0.f;
#pragma unroll
        for (int g = 0; g < 8; ++g) s2 += ssbuf[g][t];
        rnl[t] = 1.0f / fmaxf(sqrtf(s2), 1e-12f);
    }
    __syncthreads();
    const float rn = rnl[p];

    uint pk[8];
#pragma unroll
    for (int i = 0; i < 8; ++i) {
        int v = __builtin_amdgcn_cvt_pk_fp8_f32(x[4 * i] * rn, x[4 * i + 1] * rn, 0, false);
        v = __builtin_amdgcn_cvt_pk_fp8_f32(x[4 * i + 2] * rn, x[4 * i + 3] * rn, v, true);
        pk[i] = (uint)v;
    }
    uint4* o = (uint4*)(dst + (size_t)P * CC + c0);
    o[0] = make_uint4(pk[0], pk[1], pk[2], pk[3]);
    o[1] = make_uint4(pk[4], pk[5], pk[6], pk[7]);
}

// ---------------- kernel 2: 128x128-tile fp8 MFMA GEMM, triple-buffer, 1 barrier/K-step ----
// 4 waves (2x2 of 64x64), BK=64 fp8 (64-byte rows, byte-identical staging geometry to
// r12's BK=32 bf16), 3x8KB buffers per matrix (48 KB total, 3 blocks/CU), counted
// vmcnt (never 0 mid-loop), 3-deep prefetch, partial-sum epilogue (no atomics).
// Per KITER: 2 fp8 MFMA K-instructions (ki=0: K 0-31, ki=1: K 32-63); ki1 LDS addr
// = ki0 addr XOR 32 (chunk16 bit1 flip). Frag reads are ds_read_b64, <=2-way aliased.
__global__ __launch_bounds__(256, 2) void gemm_mfma(
    const unsigned char* __restrict__ Abf, const unsigned char* __restrict__ Bbf,
    const int* __restrict__ rmask, const int* __restrict__ imask,
    float2* __restrict__ prow, float2* __restrict__ pcol)
{
    __shared__ __align__(16) unsigned char As[3][128][64];   // 24 KB
    __shared__ __align__(16) unsigned char Bs[3][128][64];   // 24 KB

    const int n  = blockIdx.z;
    // XCD-aware bijective swizzle within the 32x32 slice (1024 % 8 == 0)
    const int lin = blockIdx.y * 32 + blockIdx.x;
    const int swz = (lin & 7) * 128 + (lin >> 3);
    const int qt = swz & 31, pt = swz >> 5;
    const int q0 = qt * 128, p0 = pt * 128;

    const int t  = threadIdx.x;
    const int lane = t & 63;
    const int wv = t >> 6, wr = wv >> 1, wc = wv & 1;
    const int kg = lane >> 4, rl = lane & 15;

    const unsigned char* Ab = Abf + ((size_t)n * HWD + p0) * CC;
    const unsigned char* Bb = Bbf + ((size_t)n * HWD + q0) * CC;

    // ---- hoisted stage addresses: 2 its x (A,B); 512 16B-slots per matrix per K-step ----
    // slot -> row r = slot>>2, pos = slot&3; global 16B-chunk pre-swizzled g = pos ^ ((r>>1)&3)
    const unsigned char* gA[2]; const unsigned char* gB[2];
    char* lA[2]; char* lB[2];
#pragma unroll
    for (int it = 0; it < 2; ++it) {
        int slot = it * 256 + t;
        int r = slot >> 2, pos = slot & 3;
        int g = pos ^ ((r >> 1) & 3);
        gA[it] = Ab + (size_t)r * CC + g * 16;
        gB[it] = Bb + (size_t)r * CC + g * 16;
        lA[it] = ((char*)As) + it * 4096 + (t & 192) * 16;
        lB[it] = ((char*)Bs) + it * 4096 + (t & 192) * 16;
    }
    // one buffer = 128*64 = 8192 bytes -> BUFB in {0, 8192, 16384}; C0 = K-step*64 bytes
#define STAGE(BUFB, C0)                                                        \
    {                                                                          \
        _Pragma("unroll")                                                      \
        for (int it = 0; it < 2; ++it) {                                       \
            gload16(gA[it] + (C0), lA[it] + (BUFB));                           \
            gload16(gB[it] + (C0), lB[it] + (BUFB));                           \
        }                                                                      \
    }

    // ---- hoisted fragment byte addresses (buf0, ki=0) ----
    // frag(ki,kg,row r): chunk16 = (2*ki + (kg>>1)) ^ ((r>>1)&3); byte = r*64 + chunk16*16 + (kg&1)*8
    const char* ap[4]; const char* bp[4];
#pragma unroll
    for (int mi = 0; mi < 4; ++mi) {
        int r = wr * 64 + mi * 16 + rl;
        int c16 = (kg >> 1) ^ ((r >> 1) & 3);
        ap[mi] = ((const char*)As) + r * 64 + c16 * 16 + (kg & 1) * 8;
    }
#pragma unroll
    for (int ni = 0; ni < 4; ++ni) {
        int r = wc * 64 + ni * 16 + rl;
        int c16 = (kg >> 1) ^ ((r >> 1) & 3);
        bp[ni] = ((const char*)Bs) + r * 64 + c16 * 16 + (kg & 1) * 8;
    }

    f32x4 acc[4][4];
#pragma unroll
    for (int mi = 0; mi < 4; ++mi)
#pragma unroll
        for (int ni = 0; ni < 4; ++ni) acc[mi][ni] = (f32x4){0.f, 0.f, 0.f, 0.f};

    STAGE(0, 0);         // K-step 0 -> buf0 (4 loads in flight)
    STAGE(8192, 64);     // K-step 1 -> buf1 (8)
    STAGE(16384, 128);   // K-step 2 -> buf2 (12)
    SCHED0();

#define KITER(BUFB, VMWAIT, RESTAGE)                                           \
    {                                                                          \
        VMWAIT;                                                                \
        SCHED0();                                                              \
        SBAR();                                                                \
        SCHED0();                                                              \
        RESTAGE;                                                               \
        u64 a0[4], b0[4], a1[4], b1[4];                                        \
        _Pragma("unroll")                                                      \
        for (int mi = 0; mi < 4; ++mi) {                                       \
            uintptr_t pa = (uintptr_t)(ap[mi] + (BUFB));                       \
            a0[mi] = *(const u64*)pa;                                          \
            a1[mi] = *(const u64*)(pa ^ 32);                                   \
        }                                                                      \
        _Pragma("unroll")                                                      \
        for (int ni = 0; ni < 4; ++ni) {                                       \
            uintptr_t pb = (uintptr_t)(bp[ni] + (BUFB));                       \
            b0[ni] = *(const u64*)pb;                                          \
            b1[ni] = *(const u64*)(pb ^ 32);                                   \
        }                                                                      \
        LGKM0();                                                               \
        SCHED0();                                                              \
        __builtin_amdgcn_s_setprio(1);                                         \
        _Pragma("unroll")                                                      \
        for (int mi = 0; mi < 4; ++mi)                                         \
            _Pragma("unroll")                                                  \
            for (int ni = 0; ni < 4; ++ni)                                     \
                acc[mi][ni] = __builtin_amdgcn_mfma_f32_16x16x32_fp8_fp8(      \
                    (long)a0[mi], (long)b0[ni], acc[mi][ni], 0, 0, 0);         \
        _Pragma("unroll")                                                      \
        for (int mi = 0; mi < 4; ++mi)                                         \
            _Pragma("unroll")                                                  \
            for (int ni = 0; ni < 4; ++ni)                                     \
                acc[mi][ni] = __builtin_amdgcn_mfma_f32_16x16x32_fp8_fp8(      \
                    (long)a1[mi], (long)b1[ni], acc[mi][ni], 0, 0, 0);         \
        __builtin_amdgcn_s_setprio(0);                                         \
        SCHED0();                                                              \
    }

    KITER(0,     VMW8(), );                   // step 0 (buf0); bufs 1,2 in flight
    KITER(8192,  VMW4(), STAGE(0, 192));      // step 1 (buf1); stage step3 -> buf0
    KITER(16384, VMW4(), );                   // step 2 (buf2)
    KITER(0,     VMW0(), );                   // step 3 (buf0 restaged)
#undef KITER
#undef STAGE

    // ---- epilogue: clamp, exp, mask, block-local reduce, partial store (no atomics) ----
    const int* rmp = rmask + (size_t)n * HWD + p0 + wr * 64;
    const int* imp = imask + (size_t)n * HWD + q0 + wc * 64;
    int clab[4];
#pragma unroll
    for (int ni = 0; ni < 4; ++ni) clab[ni] = imp[ni * 16 + rl];

    // LDS scratch aliasing As buf2 (last read at step 2; every wave passed step 2's
    // lgkmcnt(0) before crossing step 3's barrier). Step 3 reads buf0 only.
    float* rb = (float*)((char*)As + 16384);  // [wc][nd][128 rows] = 512 floats
    float* cb = rb + 512;                     // [wr][nd][128 cols] = 512 floats

    const float SC = 28.853900817779268f;   // 20 * log2(e)
    float cn[4] = {0.f, 0.f, 0.f, 0.f}, cd[4] = {0.f, 0.f, 0.f, 0.f};

#pragma unroll
    for (int mi = 0; mi < 4; ++mi) {
        int4 r4 = *(const int4*)(rmp + mi * 16 + kg * 4);
        int rlab[4] = {r4.x, r4.y, r4.z, r4.w};
        float rn4[4] = {0.f, 0.f, 0.f, 0.f}, rd4[4] = {0.f, 0.f, 0.f, 0.f};
#pragma unroll
        for (int ni = 0; ni < 4; ++ni) {
#pragma unroll
            for (int j = 0; j < 4; ++j) {
                float s = fminf(fmaxf(acc[mi][ni][j], -1.f), 1.f);
                float e = exp2f(s * SC);
                rd4[j] += e;
                cd[ni] += e;
                bool m = (rlab[j] == clab[ni]);
                rn4[j] += m ? e : 0.f;
                cn[ni] += m ? e : 0.f;
            }
        }
#pragma unroll
        for (int j = 0; j < 4; ++j) {
            rn4[j] = dpp_rowsum16(rn4[j]);
            rd4[j] = dpp_rowsum16(rd4[j]);
        }
        if (rl == 15) {
            int row = wr * 64 + mi * 16 + kg * 4;
#pragma unroll
            for (int j = 0; j < 4; ++j) {
                rb[(wc * 2 + 0) * 128 + row + j] = rn4[j];
                rb[(wc * 2 + 1) * 128 + row + j] = rd4[j];
            }
        }
    }
#pragma unroll
    for (int ni = 0; ni < 4; ++ni) {
        cn[ni] += __shfl_xor(cn[ni], 16); cn[ni] += __shfl_xor(cn[ni], 32);
        cd[ni] += __shfl_xor(cd[ni], 16); cd[ni] += __shfl_xor(cd[ni], 32);
    }
    if (kg == 0) {
#pragma unroll
        for (int ni = 0; ni < 4; ++ni) {
            int col = wc * 64 + ni * 16 + rl;
            cb[(wr * 2 + 0) * 128 + col] = cn[ni];
            cb[(wr * 2 + 1) * 128 + col] = cd[ni];
        }
    }
    __syncthreads();
    if (t < 128) {
        float2 r2 = make_float2(rb[t] + rb[256 + t], rb[128 + t] + rb[384 + t]);
        prow[(size_t)qt * NPIX + (size_t)n * HWD + p0 + t] = r2;
        float2 c2 = make_float2(cb[t] + cb[256 + t], cb[128 + t] + cb[384 + t]);
        pcol[(size_t)pt * NPIX + (size_t)n * HWD + q0 + t] = c2;
    }
}

// ---------------- kernel 3: reduce partials + loss entries + global reduce ----------------
__global__ __launch_bounds__(256) void loss_reduce(
    const float2* __restrict__ prow, const float2* __restrict__ pcol,
    const int* __restrict__ rmask, const int* __restrict__ imask,
    float* __restrict__ accum)
{
    __shared__ float sbuf[2][4];
    int idx = blockIdx.x * 256 + threadIdx.x;   // 0 .. 2*NPIX-1
    float num = 0.f, den = 0.f; int fg;
    if (idx < NPIX) {
        fg = rmask[idx] > 0;
#pragma unroll 8
        for (int q = 0; q < 32; ++q) {
            float2 v = prow[(size_t)q * NPIX + idx];
            num += v.x; den += v.y;
        }
    } else {
        int k = idx - NPIX;
        fg = imask[k] > 0;
#pragma unroll 8
        for (int p = 0; p < 32; ++p) {
            float2 v = pcol[(size_t)p * NPIX + k];
            num += v.x; den += v.y;
        }
    }
    float v = 0.f, cnt = 0.f;
    if (fg && num > 0.f) {
        float r = num / (den + 1e-6f);
        v = -__logf(r);
        cnt = 1.f;
    }
#pragma unroll
    for (int m = 1; m <= 32; m <<= 1) {
        v += __shfl_xor(v, m);
        cnt += __shfl_xor(cnt, m);
    }
    int lane = threadIdx.x & 63, wave = threadIdx.x >> 6;
    if (lane == 0) { sbuf[0][wave] = v; sbuf[1][wave] = cnt; }
    __syncthreads();
    if (threadIdx.x == 0) {
        atomicAdd(&accum[0], sbuf[0][0] + sbuf[0][1] + sbuf[0][2] + sbuf[0][3]);
        atomicAdd(&accum[1], sbuf[1][0] + sbuf[1][1] + sbuf[1][2] + sbuf[1][3]);
    }
}

__global__ void finalize(const float* __restrict__ accum, float* __restrict__ out) {
    out[0] = accum[0] / fmaxf(accum[1], 1.0f);
}

// ---------------- launch ----------------
extern "C" void kernel_launch(void* const* d_in, const int* in_sizes, int n_in,
                              void* d_out, int out_size, void* d_ws, size_t ws_size,
                              hipStream_t stream) {
    const float* rgb = (const float*)d_in[0];
    const float* ir  = (const float*)d_in[1];
    const int* rm = (const int*)d_in[2];
    const int* im = (const int*)d_in[3];
    float* out = (float*)d_out;

    const size_t NE = (size_t)NPIX * CC;         // 4 MB fp8 per array
    unsigned char* Abf = (unsigned char*)d_ws;
    unsigned char* Bbf = Abf + NE;
    float2* prow = (float2*)(Bbf + NE);          // 32 * NPIX float2 = 4 MB
    float2* pcol = prow + (size_t)32 * NPIX;     // 4 MB
    float* accum = (float*)(pcol + (size_t)32 * NPIX);  // 2 floats

    hipMemsetAsync(accum, 0, 2 * sizeof(float), stream);

    normcvt<<<dim3(NPIX / 64, 2), 512, 0, stream>>>(rgb, ir, Abf, Bbf);
    gemm_mfma<<<dim3(HWD / 128, HWD / 128, NB), 256, 0, stream>>>(
        Abf, Bbf, rm, im, prow, pcol);
    loss_reduce<<<(2 * NPIX) / 256, 256, 0, stream>>>(prow, pcol, rm, im, accum);
    finalize<<<1, 1, 0, stream>>>(accum, out);
}

// Round 14
// 78.151 us; speedup vs baseline: 1.3795x; 1.0034x over previous
//
#include <hip/hip_runtime.h>
#include <math.h>
#include <stdint.h>

#define NB 4
#define CC 256
#define HWD 4096
#define NPIX (NB * HWD)

typedef __attribute__((ext_vector_type(4))) float f32x4;
typedef __attribute__((ext_vector_type(2))) long i64x2;

#define VMW8()  asm volatile("s_waitcnt vmcnt(8)" ::: "memory")
#define VMW4()  asm volatile("s_waitcnt vmcnt(4)" ::: "memory")
#define VMW0()  asm volatile("s_waitcnt vmcnt(0)" ::: "memory")
#define LGKM0() asm volatile("s_waitcnt lgkmcnt(0)" ::: "memory")
#define SCHED0() __builtin_amdgcn_sched_barrier(0)
#define SBAR()  __builtin_amdgcn_s_barrier()

__device__ __forceinline__ void gload16(const void* g, void* l) {
    using GP = const __attribute__((address_space(1))) uint32_t*;
    using LP = __attribute__((address_space(3))) uint32_t*;
    __builtin_amdgcn_global_load_lds((GP)g, (LP)l, 16, 0, 0);
}

// sum over each 16-lane DPP row; result valid in lane (rl==15) of each row
__device__ __forceinline__ float dpp_rowsum16(float v) {
    v += __int_as_float(__builtin_amdgcn_update_dpp(0, __float_as_int(v), 0x111, 0xf, 0xf, true));
    v += __int_as_float(__builtin_amdgcn_update_dpp(0, __float_as_int(v), 0x112, 0xf, 0xf, true));
    v += __int_as_float(__builtin_amdgcn_update_dpp(0, __float_as_int(v), 0x114, 0xf, 0xf, true));
    v += __int_as_float(__builtin_amdgcn_update_dpp(0, __float_as_int(v), 0x118, 0xf, 0xf, true));
    return v;
}

// ---------------- kernel 1: per-pixel L2 norm + scale + fp8(e4m3) + transpose ----------------
// Output layout (k-interleaved, same permutation for A and B — dot-product invariant):
// per pixel row, 64-byte K-window w, 16B block g holds channels
// {w*64 + 8g + 0..7} (bytes 0-7) and {w*64 + 32 + 8g + 0..7} (bytes 8-15).
__global__ __launch_bounds__(512) void normcvt(
    const float* __restrict__ rgb, const float* __restrict__ ir,
    unsigned char* __restrict__ Abf, unsigned char* __restrict__ Bbf)
{
    __shared__ float ssbuf[8][64];
    __shared__ float rnl[64];
    const float* src = blockIdx.y ? ir : rgb;
    unsigned char* dst = blockIdx.y ? Bbf : Abf;
    const int t = threadIdx.x;
    const int p = t & 63, sg = t >> 6;
    const int P = blockIdx.x * 64 + p;
    const int n = P >> 12, pl = P & (HWD - 1);
    const float* base = src + ((size_t)n * CC) * HWD + pl;
    const int c0 = sg * 32;              // thread covers channels [c0, c0+32)

    float x[32];
    float ss = 0.f;
#pragma unroll
    for (int i = 0; i < 32; ++i) {
        x[i] = base[(size_t)(c0 + i) * HWD];
        ss = fmaf(x[i], x[i], ss);
    }
    ssbuf[sg][p] = ss;
    __syncthreads();
    if (t < 64) {
        float s2 = 0.f;
#pragma unroll
        for (int g = 0; g < 8; ++g) s2 += ssbuf[g][t];
        rnl[t] = 1.0f / fmaxf(sqrtf(s2), 1e-12f);
    }
    __syncthreads();
    const float rn = rnl[p];

    uint pk[8];
#pragma unroll
    for (int i = 0; i < 8; ++i) {
        int v = __builtin_amdgcn_cvt_pk_fp8_f32(x[4 * i] * rn, x[4 * i + 1] * rn, 0, false);
        v = __builtin_amdgcn_cvt_pk_fp8_f32(x[4 * i + 2] * rn, x[4 * i + 3] * rn, v, true);
        pk[i] = (uint)v;
    }
    // window w = sg>>1; lower-half threads (sg even) fill bytes 0-7 of each block,
    // upper-half threads (sg odd) fill bytes 8-15.
    uint2* o = (uint2*)(dst + (size_t)P * CC + (sg >> 1) * 64 + (sg & 1) * 8);
#pragma unroll
    for (int g = 0; g < 4; ++g)
        o[g * 2] = make_uint2(pk[2 * g], pk[2 * g + 1]);   // stride 16B between blocks
}

// ---------------- kernel 2: 128x128-tile fp8 MFMA GEMM, triple-buffer, 1 barrier/K-step ----
// 4 waves (2x2 of 64x64), BK=64 fp8 (64-byte rows), 3x8KB buffers per matrix (48 KB,
// 3 blocks/CU), counted vmcnt (never 0 mid-loop), 3-deep prefetch, partial-sum epilogue.
// Fragments: ONE ds_read_b128 per (mi/ni) at chunk kg^((r>>1)&3) — r12's zero-conflict
// pattern; low 8B = MFMA k-instr 0, high 8B = k-instr 1 (k-interleaved layout above).
__global__ __launch_bounds__(256, 2) void gemm_mfma(
    const unsigned char* __restrict__ Abf, const unsigned char* __restrict__ Bbf,
    const int* __restrict__ rmask, const int* __restrict__ imask,
    float2* __restrict__ prow, float2* __restrict__ pcol)
{
    __shared__ __align__(16) unsigned char As[3][128][64];   // 24 KB
    __shared__ __align__(16) unsigned char Bs[3][128][64];   // 24 KB

    const int n  = blockIdx.z;
    // XCD-aware bijective swizzle within the 32x32 slice (1024 % 8 == 0)
    const int lin = blockIdx.y * 32 + blockIdx.x;
    const int swz = (lin & 7) * 128 + (lin >> 3);
    const int qt = swz & 31, pt = swz >> 5;
    const int q0 = qt * 128, p0 = pt * 128;

    const int t  = threadIdx.x;
    const int lane = t & 63;
    const int wv = t >> 6, wr = wv >> 1, wc = wv & 1;
    const int kg = lane >> 4, rl = lane & 15;

    const unsigned char* Ab = Abf + ((size_t)n * HWD + p0) * CC;
    const unsigned char* Bb = Bbf + ((size_t)n * HWD + q0) * CC;

    // ---- hoisted stage addresses: 2 its x (A,B); 512 16B-slots per matrix per K-step ----
    // slot -> row r = slot>>2, pos = slot&3; global 16B-chunk pre-swizzled g = pos ^ ((r>>1)&3)
    const unsigned char* gA[2]; const unsigned char* gB[2];
    char* lA[2]; char* lB[2];
#pragma unroll
    for (int it = 0; it < 2; ++it) {
        int slot = it * 256 + t;
        int r = slot >> 2, pos = slot & 3;
        int g = pos ^ ((r >> 1) & 3);
        gA[it] = Ab + (size_t)r * CC + g * 16;
        gB[it] = Bb + (size_t)r * CC + g * 16;
        lA[it] = ((char*)As) + it * 4096 + (t & 192) * 16;
        lB[it] = ((char*)Bs) + it * 4096 + (t & 192) * 16;
    }
    // one buffer = 128*64 = 8192 bytes -> BUFB in {0, 8192, 16384}; C0 = K-step*64 bytes
#define STAGE(BUFB, C0)                                                        \
    {                                                                          \
        _Pragma("unroll")                                                      \
        for (int it = 0; it < 2; ++it) {                                       \
            gload16(gA[it] + (C0), lA[it] + (BUFB));                           \
            gload16(gB[it] + (C0), lB[it] + (BUFB));                           \
        }                                                                      \
    }

    // ---- hoisted fragment byte addresses (buf0): r*64 + (kg^((r>>1)&3))*16 ----
    const char* ap[4]; const char* bp[4];
#pragma unroll
    for (int mi = 0; mi < 4; ++mi) {
        int r = wr * 64 + mi * 16 + rl;
        ap[mi] = ((const char*)As) + r * 64 + (kg ^ ((r >> 1) & 3)) * 16;
    }
#pragma unroll
    for (int ni = 0; ni < 4; ++ni) {
        int r = wc * 64 + ni * 16 + rl;
        bp[ni] = ((const char*)Bs) + r * 64 + (kg ^ ((r >> 1) & 3)) * 16;
    }

    f32x4 acc[4][4];
#pragma unroll
    for (int mi = 0; mi < 4; ++mi)
#pragma unroll
        for (int ni = 0; ni < 4; ++ni) acc[mi][ni] = (f32x4){0.f, 0.f, 0.f, 0.f};

    STAGE(0, 0);         // K-step 0 -> buf0 (4 loads in flight)
    STAGE(8192, 64);     // K-step 1 -> buf1 (8)
    STAGE(16384, 128);   // K-step 2 -> buf2 (12)
    SCHED0();

#define KITER(BUFB, VMWAIT, RESTAGE)                                           \
    {                                                                          \
        VMWAIT;                                                                \
        SCHED0();                                                              \
        SBAR();                                                                \
        SCHED0();                                                              \
        RESTAGE;                                                               \
        i64x2 aa[4], bb[4];                                                    \
        _Pragma("unroll")                                                      \
        for (int mi = 0; mi < 4; ++mi)                                         \
            aa[mi] = *(const i64x2*)(ap[mi] + (BUFB));                         \
        _Pragma("unroll")                                                      \
        for (int ni = 0; ni < 4; ++ni)                                         \
            bb[ni] = *(const i64x2*)(bp[ni] + (BUFB));                         \
        LGKM0();                                                               \
        SCHED0();                                                              \
        __builtin_amdgcn_s_setprio(1);                                         \
        _Pragma("unroll")                                                      \
        for (int mi = 0; mi < 4; ++mi)                                         \
            _Pragma("unroll")                                                  \
            for (int ni = 0; ni < 4; ++ni)                                     \
                acc[mi][ni] = __builtin_amdgcn_mfma_f32_16x16x32_fp8_fp8(      \
                    aa[mi][0], bb[ni][0], acc[mi][ni], 0, 0, 0);               \
        _Pragma("unroll")                                                      \
        for (int mi = 0; mi < 4; ++mi)                                         \
            _Pragma("unroll")                                                  \
            for (int ni = 0; ni < 4; ++ni)                                     \
                acc[mi][ni] = __builtin_amdgcn_mfma_f32_16x16x32_fp8_fp8(      \
                    aa[mi][1], bb[ni][1], acc[mi][ni], 0, 0, 0);               \
        __builtin_amdgcn_s_setprio(0);                                         \
        SCHED0();                                                              \
    }

    KITER(0,     VMW8(), );                   // step 0 (buf0); bufs 1,2 in flight
    KITER(8192,  VMW4(), STAGE(0, 192));      // step 1 (buf1); stage step3 -> buf0
    KITER(16384, VMW4(), );                   // step 2 (buf2)
    KITER(0,     VMW0(), );                   // step 3 (buf0 restaged)
#undef KITER
#undef STAGE

    // ---- epilogue: clamp, exp, mask, block-local reduce, partial store (no atomics) ----
    const int* rmp = rmask + (size_t)n * HWD + p0 + wr * 64;
    const int* imp = imask + (size_t)n * HWD + q0 + wc * 64;
    int clab[4];
#pragma unroll
    for (int ni = 0; ni < 4; ++ni) clab[ni] = imp[ni * 16 + rl];

    // LDS scratch aliasing As buf2 (last read at step 2; every wave passed step 2's
    // lgkmcnt(0) before crossing step 3's barrier). Step 3 reads buf0 only.
    float* rb = (float*)((char*)As + 16384);  // [wc][nd][128 rows] = 512 floats
    float* cb = rb + 512;                     // [wr][nd][128 cols] = 512 floats

    const float SC = 28.853900817779268f;   // 20 * log2(e)
    float cn[4] = {0.f, 0.f, 0.f, 0.f}, cd[4] = {0.f, 0.f, 0.f, 0.f};

#pragma unroll
    for (int mi = 0; mi < 4; ++mi) {
        int4 r4 = *(const int4*)(rmp + mi * 16 + kg * 4);
        int rlab[4] = {r4.x, r4.y, r4.z, r4.w};
        float rn4[4] = {0.f, 0.f, 0.f, 0.f}, rd4[4] = {0.f, 0.f, 0.f, 0.f};
#pragma unroll
        for (int ni = 0; ni < 4; ++ni) {
#pragma unroll
            for (int j = 0; j < 4; ++j) {
                float s = fminf(fmaxf(acc[mi][ni][j], -1.f), 1.f);
                float e = exp2f(s * SC);
                rd4[j] += e;
                cd[ni] += e;
                bool m = (rlab[j] == clab[ni]);
                rn4[j] += m ? e : 0.f;
                cn[ni] += m ? e : 0.f;
            }
        }
#pragma unroll
        for (int j = 0; j < 4; ++j) {
            rn4[j] = dpp_rowsum16(rn4[j]);
            rd4[j] = dpp_rowsum16(rd4[j]);
        }
        if (rl == 15) {
            int row = wr * 64 + mi * 16 + kg * 4;
#pragma unroll
            for (int j = 0; j < 4; ++j) {
                rb[(wc * 2 + 0) * 128 + row + j] = rn4[j];
                rb[(wc * 2 + 1) * 128 + row + j] = rd4[j];
            }
        }
    }
#pragma unroll
    for (int ni = 0; ni < 4; ++ni) {
        cn[ni] += __shfl_xor(cn[ni], 16); cn[ni] += __shfl_xor(cn[ni], 32);
        cd[ni] += __shfl_xor(cd[ni], 16); cd[ni] += __shfl_xor(cd[ni], 32);
    }
    if (kg == 0) {
#pragma unroll
        for (int ni = 0; ni < 4; ++ni) {
            int col = wc * 64 + ni * 16 + rl;
            cb[(wr * 2 + 0) * 128 + col] = cn[ni];
            cb[(wr * 2 + 1) * 128 + col] = cd[ni];
        }
    }
    __syncthreads();
    if (t < 128) {
        float2 r2 = make_float2(rb[t] + rb[256 + t], rb[128 + t] + rb[384 + t]);
        prow[(size_t)qt * NPIX + (size_t)n * HWD + p0 + t] = r2;
        float2 c2 = make_float2(cb[t] + cb[256 + t], cb[128 + t] + cb[384 + t]);
        pcol[(size_t)pt * NPIX + (size_t)n * HWD + q0 + t] = c2;
    }
}

// ---------------- kernel 3: reduce partials + loss entries + global reduce ----------------
__global__ __launch_bounds__(256) void loss_reduce(
    const float2* __restrict__ prow, const float2* __restrict__ pcol,
    const int* __restrict__ rmask, const int* __restrict__ imask,
    float* __restrict__ accum)
{
    __shared__ float sbuf[2][4];
    int idx = blockIdx.x * 256 + threadIdx.x;   // 0 .. 2*NPIX-1
    float num = 0.f, den = 0.f; int fg;
    if (idx < NPIX) {
        fg = rmask[idx] > 0;
#pragma unroll 8
        for (int q = 0; q < 32; ++q) {
            float2 v = prow[(size_t)q * NPIX + idx];
            num += v.x; den += v.y;
        }
    } else {
        int k = idx - NPIX;
        fg = imask[k] > 0;
#pragma unroll 8
        for (int p = 0; p < 32; ++p) {
            float2 v = pcol[(size_t)p * NPIX + k];
            num += v.x; den += v.y;
        }
    }
    float v = 0.f, cnt = 0.f;
    if (fg && num > 0.f) {
        float r = num / (den + 1e-6f);
        v = -__logf(r);
        cnt = 1.f;
    }
#pragma unroll
    for (int m = 1; m <= 32; m <<= 1) {
        v += __shfl_xor(v, m);
        cnt += __shfl_xor(cnt, m);
    }
    int lane = threadIdx.x & 63, wave = threadIdx.x >> 6;
    if (lane == 0) { sbuf[0][wave] = v; sbuf[1][wave] = cnt; }
    __syncthreads();
    if (threadIdx.x == 0) {
        atomicAdd(&accum[0], sbuf[0][0] + sbuf[0][1] + sbuf[0][2] + sbuf[0][3]);
        atomicAdd(&accum[1], sbuf[1][0] + sbuf[1][1] + sbuf[1][2] + sbuf[1][3]);
    }
}

__global__ void finalize(const float* __restrict__ accum, float* __restrict__ out) {
    out[0] = accum[0] / fmaxf(accum[1], 1.0f);
}

// ---------------- launch ----------------
extern "C" void kernel_launch(void* const* d_in, const int* in_sizes, int n_in,
                              void* d_out, int out_size, void* d_ws, size_t ws_size,
                              hipStream_t stream) {
    const float* rgb = (const float*)d_in[0];
    const float* ir  = (const float*)d_in[1];
    const int* rm = (const int*)d_in[2];
    const int* im = (const int*)d_in[3];
    float* out = (float*)d_out;

    const size_t NE = (size_t)NPIX * CC;         // 4 MB fp8 per array
    unsigned char* Abf = (unsigned char*)d_ws;
    unsigned char* Bbf = Abf + NE;
    float2* prow = (float2*)(Bbf + NE);          // 32 * NPIX float2 = 4 MB
    float2* pcol = prow + (size_t)32 * NPIX;     // 4 MB
    float* accum = (float*)(pcol + (size_t)32 * NPIX);  // 2 floats

    hipMemsetAsync(accum, 0, 2 * sizeof(float), stream);

    normcvt<<<dim3(NPIX / 64, 2), 512, 0, stream>>>(rgb, ir, Abf, Bbf);
    gemm_mfma<<<dim3(HWD / 128, HWD / 128, NB), 256, 0, stream>>>(
        Abf, Bbf, rm, im, prow, pcol);
    loss_reduce<<<(2 * NPIX) / 256, 256, 0, stream>>>(prow, pcol, rm, im, accum);
    finalize<<<1, 1, 0, stream>>>(accum, out);
}

// Round 15
// 75.817 us; speedup vs baseline: 1.4219x; 1.0308x over previous
//
#include <hip/hip_runtime.h>
#include <math.h>
#include <stdint.h>

#define NB 4
#define CC 256
#define HWD 4096
#define NPIX (NB * HWD)

typedef __attribute__((ext_vector_type(4))) float f32x4;
typedef __attribute__((ext_vector_type(2))) long i64x2;

#define VMW4()  asm volatile("s_waitcnt vmcnt(4)" ::: "memory")
#define VMW0()  asm volatile("s_waitcnt vmcnt(0)" ::: "memory")
#define LGKM0() asm volatile("s_waitcnt lgkmcnt(0)" ::: "memory")
#define SCHED0() __builtin_amdgcn_sched_barrier(0)
#define SBAR()  __builtin_amdgcn_s_barrier()

__device__ __forceinline__ void gload16(const void* g, void* l) {
    using GP = const __attribute__((address_space(1))) uint32_t*;
    using LP = __attribute__((address_space(3))) uint32_t*;
    __builtin_amdgcn_global_load_lds((GP)g, (LP)l, 16, 0, 0);
}

// sum over each 16-lane DPP row; result valid in lane (rl==15) of each row
__device__ __forceinline__ float dpp_rowsum16(float v) {
    v += __int_as_float(__builtin_amdgcn_update_dpp(0, __float_as_int(v), 0x111, 0xf, 0xf, true));
    v += __int_as_float(__builtin_amdgcn_update_dpp(0, __float_as_int(v), 0x112, 0xf, 0xf, true));
    v += __int_as_float(__builtin_amdgcn_update_dpp(0, __float_as_int(v), 0x114, 0xf, 0xf, true));
    v += __int_as_float(__builtin_amdgcn_update_dpp(0, __float_as_int(v), 0x118, 0xf, 0xf, true));
    return v;
}

// ---------------- kernel 1: per-pixel L2 norm + scale + fp8(e4m3) + transpose ----------------
// Output layout (k-interleaved, same permutation for A and B — dot-product invariant):
// per pixel row, 64-byte K-window w, 16B block g holds channels
// {w*64 + 8g + 0..7} (bytes 0-7) and {w*64 + 32 + 8g + 0..7} (bytes 8-15).
__global__ __launch_bounds__(512) void normcvt(
    const float* __restrict__ rgb, const float* __restrict__ ir,
    unsigned char* __restrict__ Abf, unsigned char* __restrict__ Bbf)
{
    __shared__ float ssbuf[8][64];
    __shared__ float rnl[64];
    const float* src = blockIdx.y ? ir : rgb;
    unsigned char* dst = blockIdx.y ? Bbf : Abf;
    const int t = threadIdx.x;
    const int p = t & 63, sg = t >> 6;
    const int P = blockIdx.x * 64 + p;
    const int n = P >> 12, pl = P & (HWD - 1);
    const float* base = src + ((size_t)n * CC) * HWD + pl;
    const int c0 = sg * 32;              // thread covers channels [c0, c0+32)

    float x[32];
    float ss = 0.f;
#pragma unroll
    for (int i = 0; i < 32; ++i) {
        x[i] = base[(size_t)(c0 + i) * HWD];
        ss = fmaf(x[i], x[i], ss);
    }
    ssbuf[sg][p] = ss;
    __syncthreads();
    if (t < 64) {
        float s2 = 0.f;
#pragma unroll
        for (int g = 0; g < 8; ++g) s2 += ssbuf[g][t];
        rnl[t] = 1.0f / fmaxf(sqrtf(s2), 1e-12f);
    }
    __syncthreads();
    const float rn = rnl[p];

    uint pk[8];
#pragma unroll
    for (int i = 0; i < 8; ++i) {
        int v = __builtin_amdgcn_cvt_pk_fp8_f32(x[4 * i] * rn, x[4 * i + 1] * rn, 0, false);
        v = __builtin_amdgcn_cvt_pk_fp8_f32(x[4 * i + 2] * rn, x[4 * i + 3] * rn, v, true);
        pk[i] = (uint)v;
    }
    // window w = sg>>1; lower-half threads (sg even) fill bytes 0-7 of each block,
    // upper-half threads (sg odd) fill bytes 8-15.
    uint2* o = (uint2*)(dst + (size_t)P * CC + (sg >> 1) * 64 + (sg & 1) * 8);
#pragma unroll
    for (int g = 0; g < 4; ++g)
        o[g * 2] = make_uint2(pk[2 * g], pk[2 * g + 1]);   // stride 16B between blocks
}

// ---------------- kernel 2: 128x128-tile fp8 MFMA GEMM, double-buffer (32KB LDS) ----------------
// 4 waves (2x2 of 64x64), BK=64 fp8 (64-byte rows), 2x8KB buffers per matrix = 32 KB
// total -> 4 blocks/CU (VGPR=76-capped). Counted vmcnt(4) (never 0 mid-loop), restage
// into the just-freed buffer after lgkm0+barrier (r5 ordering). Fragments: ONE
// ds_read_b128 per (mi/ni) at chunk kg^((r>>1)&3) — zero-conflict (measured r14);
// low 8B = MFMA k-instr 0, high 8B = k-instr 1 (k-interleaved layout above).
__global__ __launch_bounds__(256, 2) void gemm_mfma(
    const unsigned char* __restrict__ Abf, const unsigned char* __restrict__ Bbf,
    const int* __restrict__ rmask, const int* __restrict__ imask,
    float2* __restrict__ prow, float2* __restrict__ pcol)
{
    __shared__ __align__(16) unsigned char As[2][128][64];   // 16 KB
    __shared__ __align__(16) unsigned char Bs[2][128][64];   // 16 KB

    const int n  = blockIdx.z;
    // XCD-aware bijective swizzle within the 32x32 slice (1024 % 8 == 0)
    const int lin = blockIdx.y * 32 + blockIdx.x;
    const int swz = (lin & 7) * 128 + (lin >> 3);
    const int qt = swz & 31, pt = swz >> 5;
    const int q0 = qt * 128, p0 = pt * 128;

    const int t  = threadIdx.x;
    const int lane = t & 63;
    const int wv = t >> 6, wr = wv >> 1, wc = wv & 1;
    const int kg = lane >> 4, rl = lane & 15;

    const unsigned char* Ab = Abf + ((size_t)n * HWD + p0) * CC;
    const unsigned char* Bb = Bbf + ((size_t)n * HWD + q0) * CC;

    // ---- hoisted stage addresses: 2 its x (A,B); 512 16B-slots per matrix per K-step ----
    // slot -> row r = slot>>2, pos = slot&3; global 16B-chunk pre-swizzled g = pos ^ ((r>>1)&3)
    const unsigned char* gA[2]; const unsigned char* gB[2];
    char* lA[2]; char* lB[2];
#pragma unroll
    for (int it = 0; it < 2; ++it) {
        int slot = it * 256 + t;
        int r = slot >> 2, pos = slot & 3;
        int g = pos ^ ((r >> 1) & 3);
        gA[it] = Ab + (size_t)r * CC + g * 16;
        gB[it] = Bb + (size_t)r * CC + g * 16;
        lA[it] = ((char*)As) + it * 4096 + (t & 192) * 16;
        lB[it] = ((char*)Bs) + it * 4096 + (t & 192) * 16;
    }
    // one buffer = 128*64 = 8192 bytes -> BUFB in {0, 8192}; C0 = K-step*64 bytes
#define STAGE(BUFB, C0)                                                        \
    {                                                                          \
        _Pragma("unroll")                                                      \
        for (int it = 0; it < 2; ++it) {                                       \
            gload16(gA[it] + (C0), lA[it] + (BUFB));                           \
            gload16(gB[it] + (C0), lB[it] + (BUFB));                           \
        }                                                                      \
    }

    // ---- hoisted fragment byte addresses (buf0): r*64 + (kg^((r>>1)&3))*16 ----
    const char* ap[4]; const char* bp[4];
#pragma unroll
    for (int mi = 0; mi < 4; ++mi) {
        int r = wr * 64 + mi * 16 + rl;
        ap[mi] = ((const char*)As) + r * 64 + (kg ^ ((r >> 1) & 3)) * 16;
    }
#pragma unroll
    for (int ni = 0; ni < 4; ++ni) {
        int r = wc * 64 + ni * 16 + rl;
        bp[ni] = ((const char*)Bs) + r * 64 + (kg ^ ((r >> 1) & 3)) * 16;
    }

    f32x4 acc[4][4];
#pragma unroll
    for (int mi = 0; mi < 4; ++mi)
#pragma unroll
        for (int ni = 0; ni < 4; ++ni) acc[mi][ni] = (f32x4){0.f, 0.f, 0.f, 0.f};

    STAGE(0, 0);        // K-step 0 -> buf0 (4 loads in flight)
    STAGE(8192, 64);    // K-step 1 -> buf1 (8 in flight)
    SCHED0();

    // KITER: wait this buffer staged -> barrier -> ds_read frags -> lgkm0 ->
    // barrier (all waves done reading) -> restage this buffer -> MFMA.
#define KITER(BUFB, VMWAIT, RESTAGE)                                           \
    {                                                                          \
        VMWAIT;                                                                \
        SCHED0();                                                              \
        SBAR();                                                                \
        SCHED0();                                                              \
        i64x2 aa[4], bb[4];                                                    \
        _Pragma("unroll")                                                      \
        for (int mi = 0; mi < 4; ++mi)                                         \
            aa[mi] = *(const i64x2*)(ap[mi] + (BUFB));                         \
        _Pragma("unroll")                                                      \
        for (int ni = 0; ni < 4; ++ni)                                         \
            bb[ni] = *(const i64x2*)(bp[ni] + (BUFB));                         \
        LGKM0();                                                               \
        SCHED0();                                                              \
        SBAR();                                                                \
        SCHED0();                                                              \
        RESTAGE;                                                               \
        __builtin_amdgcn_s_setprio(1);                                         \
        _Pragma("unroll")                                                      \
        for (int mi = 0; mi < 4; ++mi)                                         \
            _Pragma("unroll")                                                  \
            for (int ni = 0; ni < 4; ++ni)                                     \
                acc[mi][ni] = __builtin_amdgcn_mfma_f32_16x16x32_fp8_fp8(      \
                    aa[mi][0], bb[ni][0], acc[mi][ni], 0, 0, 0);               \
        _Pragma("unroll")                                                      \
        for (int mi = 0; mi < 4; ++mi)                                         \
            _Pragma("unroll")                                                  \
            for (int ni = 0; ni < 4; ++ni)                                     \
                acc[mi][ni] = __builtin_amdgcn_mfma_f32_16x16x32_fp8_fp8(      \
                    aa[mi][1], bb[ni][1], acc[mi][ni], 0, 0, 0);               \
        __builtin_amdgcn_s_setprio(0);                                         \
        SCHED0();                                                              \
    }

    KITER(0,    VMW4(), STAGE(0, 128));       // step 0 (buf0); restage step2 -> buf0
    KITER(8192, VMW4(), STAGE(8192, 192));    // step 1 (buf1); restage step3 -> buf1
    KITER(0,    VMW4(), );                    // step 2 (buf0)
    KITER(8192, VMW0(), );                    // step 3 (buf1)
#undef KITER
#undef STAGE

    // ---- epilogue: clamp, exp, mask, block-local reduce, partial store (no atomics) ----
    const int* rmp = rmask + (size_t)n * HWD + p0 + wr * 64;
    const int* imp = imask + (size_t)n * HWD + q0 + wc * 64;
    int clab[4];
#pragma unroll
    for (int ni = 0; ni < 4; ++ni) clab[ni] = imp[ni * 16 + rl];

    // LDS scratch aliasing As buf0 (last read at step 2; every wave passed step 2's
    // second barrier — which follows all buf0 lgkm0 drains — before reaching here).
    float* rb = (float*)As;      // [wc][nd][128 rows] = 512 floats
    float* cb = rb + 512;        // [wr][nd][128 cols] = 512 floats

    const float SC = 28.853900817779268f;   // 20 * log2(e)
    float cn[4] = {0.f, 0.f, 0.f, 0.f}, cd[4] = {0.f, 0.f, 0.f, 0.f};

#pragma unroll
    for (int mi = 0; mi < 4; ++mi) {
        int4 r4 = *(const int4*)(rmp + mi * 16 + kg * 4);
        int rlab[4] = {r4.x, r4.y, r4.z, r4.w};
        float rn4[4] = {0.f, 0.f, 0.f, 0.f}, rd4[4] = {0.f, 0.f, 0.f, 0.f};
#pragma unroll
        for (int ni = 0; ni < 4; ++ni) {
#pragma unroll
            for (int j = 0; j < 4; ++j) {
                float s = fminf(fmaxf(acc[mi][ni][j], -1.f), 1.f);
                float e = exp2f(s * SC);
                rd4[j] += e;
                cd[ni] += e;
                bool m = (rlab[j] == clab[ni]);
                rn4[j] += m ? e : 0.f;
                cn[ni] += m ? e : 0.f;
            }
        }
#pragma unroll
        for (int j = 0; j < 4; ++j) {
            rn4[j] = dpp_rowsum16(rn4[j]);
            rd4[j] = dpp_rowsum16(rd4[j]);
        }
        if (rl == 15) {
            int row = wr * 64 + mi * 16 + kg * 4;
#pragma unroll
            for (int j = 0; j < 4; ++j) {
                rb[(wc * 2 + 0) * 128 + row + j] = rn4[j];
                rb[(wc * 2 + 1) * 128 + row + j] = rd4[j];
            }
        }
    }
#pragma unroll
    for (int ni = 0; ni < 4; ++ni) {
        cn[ni] += __shfl_xor(cn[ni], 16); cn[ni] += __shfl_xor(cn[ni], 32);
        cd[ni] += __shfl_xor(cd[ni], 16); cd[ni] += __shfl_xor(cd[ni], 32);
    }
    if (kg == 0) {
#pragma unroll
        for (int ni = 0; ni < 4; ++ni) {
            int col = wc * 64 + ni * 16 + rl;
            cb[(wr * 2 + 0) * 128 + col] = cn[ni];
            cb[(wr * 2 + 1) * 128 + col] = cd[ni];
        }
    }
    __syncthreads();
    if (t < 128) {
        float2 r2 = make_float2(rb[t] + rb[256 + t], rb[128 + t] + rb[384 + t]);
        prow[(size_t)qt * NPIX + (size_t)n * HWD + p0 + t] = r2;
        float2 c2 = make_float2(cb[t] + cb[256 + t], cb[128 + t] + cb[384 + t]);
        pcol[(size_t)pt * NPIX + (size_t)n * HWD + q0 + t] = c2;
    }
}

// ---------------- kernel 3: reduce partials + loss entries + global reduce ----------------
__global__ __launch_bounds__(256) void loss_reduce(
    const float2* __restrict__ prow, const float2* __restrict__ pcol,
    const int* __restrict__ rmask, const int* __restrict__ imask,
    float* __restrict__ accum)
{
    __shared__ float sbuf[2][4];
    int idx = blockIdx.x * 256 + threadIdx.x;   // 0 .. 2*NPIX-1
    float num = 0.f, den = 0.f; int fg;
    if (idx < NPIX) {
        fg = rmask[idx] > 0;
#pragma unroll 8
        for (int q = 0; q < 32; ++q) {
            float2 v = prow[(size_t)q * NPIX + idx];
            num += v.x; den += v.y;
        }
    } else {
        int k = idx - NPIX;
        fg = imask[k] > 0;
#pragma unroll 8
        for (int p = 0; p < 32; ++p) {
            float2 v = pcol[(size_t)p * NPIX + k];
            num += v.x; den += v.y;
        }
    }
    float v = 0.f, cnt = 0.f;
    if (fg && num > 0.f) {
        float r = num / (den + 1e-6f);
        v = -__logf(r);
        cnt = 1.f;
    }
#pragma unroll
    for (int m = 1; m <= 32; m <<= 1) {
        v += __shfl_xor(v, m);
        cnt += __shfl_xor(cnt, m);
    }
    int lane = threadIdx.x & 63, wave = threadIdx.x >> 6;
    if (lane == 0) { sbuf[0][wave] = v; sbuf[1][wave] = cnt; }
    __syncthreads();
    if (threadIdx.x == 0) {
        atomicAdd(&accum[0], sbuf[0][0] + sbuf[0][1] + sbuf[0][2] + sbuf[0][3]);
        atomicAdd(&accum[1], sbuf[1][0] + sbuf[1][1] + sbuf[1][2] + sbuf[1][3]);
    }
}

__global__ void finalize(const float* __restrict__ accum, float* __restrict__ out) {
    out[0] = accum[0] / fmaxf(accum[1], 1.0f);
}

// ---------------- launch ----------------
extern "C" void kernel_launch(void* const* d_in, const int* in_sizes, int n_in,
                              void* d_out, int out_size, void* d_ws, size_t ws_size,
                              hipStream_t stream) {
    const float* rgb = (const float*)d_in[0];
    const float* ir  = (const float*)d_in[1];
    const int* rm = (const int*)d_in[2];
    const int* im = (const int*)d_in[3];
    float* out = (float*)d_out;

    const size_t NE = (size_t)NPIX * CC;         // 4 MB fp8 per array
    unsigned char* Abf = (unsigned char*)d_ws;
    unsigned char* Bbf = Abf + NE;
    float2* prow = (float2*)(Bbf + NE);          // 32 * NPIX float2 = 4 MB
    float2* pcol = prow + (size_t)32 * NPIX;     // 4 MB
    float* accum = (float*)(pcol + (size_t)32 * NPIX);  // 2 floats

    hipMemsetAsync(accum, 0, 2 * sizeof(float), stream);

    normcvt<<<dim3(NPIX / 64, 2), 512, 0, stream>>>(rgb, ir, Abf, Bbf);
    gemm_mfma<<<dim3(HWD / 128, HWD / 128, NB), 256, 0, stream>>>(
        Abf, Bbf, rm, im, prow, pcol);
    loss_reduce<<<(2 * NPIX) / 256, 256, 0, stream>>>(prow, pcol, rm, im, accum);
    finalize<<<1, 1, 0, stream>>>(accum, out);
}